// Round 1
// baseline (6584.393 us; speedup 1.0000x reference)
//
#include <hip/hip_runtime.h>
#include <hip/hip_bf16.h>
#include <stdint.h>

#define TT 64
#define BB 512
#define XX 1024
#define HH 1024
#define ZZ 256
#define AA 64

typedef __bf16 bf16;
typedef bf16 bf16x8 __attribute__((ext_vector_type(8)));
typedef float f32x4 __attribute__((ext_vector_type(4)));

// d_out layout (fp32): beliefs[T+1,B,H] | q_loc | q_scale | p_loc | p_scale | z_q (each [T,B,Z])
#define SZ_BEL ((long)(TT + 1) * BB * HH)
#define SZ_TBZ ((long)TT * BB * ZZ)
#define OFF_QL (SZ_BEL)
#define OFF_QS (OFF_QL + SZ_TBZ)
#define OFF_ZQ (OFF_QL + 4 * SZ_TBZ)

#define GLL16(g, l)                                                         \
  __builtin_amdgcn_global_load_lds(                                         \
      (__attribute__((address_space(1))) void*)(g),                         \
      (__attribute__((address_space(3))) void*)(l), 16, 0, 0)

__device__ __forceinline__ float eluf(float x) {
  return x > 0.f ? x : expf(x) - 1.f;
}
__device__ __forceinline__ float splusf(float x) {
  return fmaxf(x, 0.f) + log1pf(expf(-fabsf(x)));
}
__device__ __forceinline__ float sigf(float x) {
  return 1.f / (1.f + expf(-x));
}

struct GArgs {
  const bf16* A; const float* Af; const bf16* A2;
  long lda, lda2; int ksplit;
  const bf16* Bt;
  int M, N, K, t;
  const float *b_q1, *b_p1, *b_ghh, *b_gih;
  const float *b_qm, *b_qs, *b_pm, *b_ps, *b_ag;
  const bf16* obs_pre;
  bf16 *hid_q, *hid_p, *a_buf, *out_bf;
  float *gh, *gi, *dout;
};

// EPI: 0 = store bf16 (obs_pre precompute)
//      1 = h-block: [hid_q w/ obs_pre+elu | hid_p elu | gh raw]
//      2 = heads:   [q_loc | softplus q_scale | p_loc | softplus p_scale] -> d_out
//      3 = aggr:    elu -> a_buf              4 = gi raw
template <int BM, int BN, int EPI, bool AF32>
__global__ __launch_bounds__(256) void gemm_k(GArgs g) {
  constexpr int BK = 32;
  constexpr int WTM = BM / 2, WTN = BN / 2;
  constexpr int MR = WTM / 16, NR = WTN / 16;
  constexpr int CA = BM * 4 / 256, CB = BN * 4 / 256;
  __shared__ bf16 sA[BM * BK];
  __shared__ bf16 sB[BN * BK];
  const int nbm = g.M / BM;
  const int bm = blockIdx.x % nbm, bn = blockIdx.x / nbm;
  const int m0 = bm * BM, n0 = bn * BN;
  const int tid = threadIdx.x;
  const int wid = tid >> 6, lane = tid & 63;
  const int wm = wid & 1, wn = wid >> 1;
  const int lr = lane & 15, lk = lane >> 4;

  const bf16* Ap = g.A;
  if (EPI == 2 && n0 >= 512) Ap = g.A2;  // hid_p half

  f32x4 acc[MR][NR] = {};

  for (int k0 = 0; k0 < g.K; k0 += BK) {
    __syncthreads();
    if constexpr (AF32) {
#pragma unroll
      for (int i = 0; i < CA; i++) {
        int c = tid + i * 256, row = c >> 2, kc = c & 3;
        const float* s = g.Af + (long)(m0 + row) * g.lda + k0 + kc * 8;
        float4 v0 = *(const float4*)s;
        float4 v1 = *(const float4*)(s + 4);
        bf16x8 p;
        p[0] = (bf16)v0.x; p[1] = (bf16)v0.y; p[2] = (bf16)v0.z; p[3] = (bf16)v0.w;
        p[4] = (bf16)v1.x; p[5] = (bf16)v1.y; p[6] = (bf16)v1.z; p[7] = (bf16)v1.w;
        *(bf16x8*)&sA[c * 8] = p;
      }
    } else {
#pragma unroll
      for (int i = 0; i < CA; i++) {
        int c = tid + i * 256, row = c >> 2, kc = c & 3;
        const bf16* s;
        if (EPI == 3 && k0 >= g.ksplit)
          s = g.A2 + (long)(m0 + row) * g.lda2 + (k0 - g.ksplit) + kc * 8;
        else
          s = Ap + (long)(m0 + row) * g.lda + k0 + kc * 8;
        GLL16(s, &sA[c * 8]);
      }
    }
#pragma unroll
    for (int i = 0; i < CB; i++) {
      int c = tid + i * 256, row = c >> 2, kc = c & 3;
      GLL16(g.Bt + (long)(n0 + row) * g.K + k0 + kc * 8, &sB[c * 8]);
    }
    __syncthreads();
    bf16x8 af[MR];
#pragma unroll
    for (int mi = 0; mi < MR; mi++)
      af[mi] = *(const bf16x8*)&sA[(wm * WTM + mi * 16 + lr) * BK + lk * 8];
#pragma unroll
    for (int nj = 0; nj < NR; nj++) {
      bf16x8 bfr = *(const bf16x8*)&sB[(wn * WTN + nj * 16 + lr) * BK + lk * 8];
#pragma unroll
      for (int mi = 0; mi < MR; mi++)
        acc[mi][nj] = __builtin_amdgcn_mfma_f32_16x16x32_bf16(af[mi], bfr, acc[mi][nj], 0, 0, 0);
    }
  }

#pragma unroll
  for (int mi = 0; mi < MR; mi++) {
#pragma unroll
    for (int nj = 0; nj < NR; nj++) {
#pragma unroll
      for (int r = 0; r < 4; r++) {
        const int row = m0 + wm * WTM + mi * 16 + lk * 4 + r;
        const int col = n0 + wn * WTN + nj * 16 + lr;
        float v = acc[mi][nj][r];
        if constexpr (EPI == 0) {
          g.out_bf[(long)row * g.N + col] = (bf16)v;
        } else if constexpr (EPI == 1) {
          if (col < HH) {
            float x = v + g.b_q1[col] + (float)g.obs_pre[((long)g.t * BB + row) * HH + col];
            g.hid_q[row * HH + col] = (bf16)eluf(x);
          } else if (col < 2 * HH) {
            int j = col - HH;
            g.hid_p[row * HH + j] = (bf16)eluf(v + g.b_p1[j]);
          } else {
            int j = col - 2 * HH;
            g.gh[(long)row * 3 * HH + j] = v + g.b_ghh[j];
          }
        } else if constexpr (EPI == 2) {
          int region = col >> 8, j = col & 255;
          const float* bias = region == 0 ? g.b_qm : region == 1 ? g.b_qs
                            : region == 2 ? g.b_pm : g.b_ps;
          float x = v + bias[j];
          if (region & 1) x = splusf(x);
          g.dout[OFF_QL + (long)region * SZ_TBZ + ((long)g.t * BB + row) * ZZ + j] = x;
        } else if constexpr (EPI == 3) {
          g.a_buf[row * HH + col] = (bf16)eluf(v + g.b_ag[col]);
        } else {
          g.gi[(long)row * 3 * HH + col] = v + g.b_gih[col];
        }
      }
    }
  }
}

// dst[n*K + k] = bf16(src[(k + k_off)*ld + n]); grid (N/32, K/32), block (32,8)
__global__ void transpose_cvt(const float* __restrict__ src, bf16* __restrict__ dst,
                              int K, int N, int ld, int k_off) {
  __shared__ float tile[32][33];
  const int nb = blockIdx.x * 32, kb = blockIdx.y * 32;
  const int tx = threadIdx.x, ty = threadIdx.y;
#pragma unroll
  for (int j = 0; j < 32; j += 8)
    tile[ty + j][tx] = src[(long)(kb + ty + j + k_off) * ld + nb + tx];
  __syncthreads();
#pragma unroll
  for (int j = 0; j < 32; j += 8)
    dst[(long)(nb + ty + j) * K + kb + tx] = (bf16)tile[tx][ty + j];
}

__global__ void cvt_bf16(const float* __restrict__ src, bf16* __restrict__ dst, long n) {
  long i = ((long)blockIdx.x * blockDim.x + threadIdx.x) * 4;
  if (i < n) {
    float4 v = *(const float4*)(src + i);
    dst[i] = (bf16)v.x; dst[i + 1] = (bf16)v.y;
    dst[i + 2] = (bf16)v.z; dst[i + 3] = (bf16)v.w;
  }
}

__global__ void init_k(bf16* hbf, float* dout) {
  int i = blockIdx.x * 256 + threadIdx.x;
  hbf[i] = (bf16)0.f;
  dout[i] = 0.f;  // beliefs[0] = h0 = 0
}

__global__ void zq_k(const float* __restrict__ eps, float* dout, bf16* zbf, int t) {
  long i = (long)blockIdx.x * 256 + threadIdx.x;  // over B*Z
  long o = (long)t * BB * ZZ + i;
  float ql = dout[OFF_QL + o], qs = dout[OFF_QS + o];
  float z = ql + qs * eps[o];
  dout[OFF_ZQ + o] = z;
  zbf[i] = (bf16)z;
}

__global__ void gates_k(const float* __restrict__ gi, const float* __restrict__ gh,
                        bf16* hbf, float* dout, int t) {
  long i = (long)blockIdx.x * 256 + threadIdx.x;  // over B*H
  int m = (int)(i >> 10), j = (int)(i & 1023);
  long b = (long)m * 3 * HH + j;
  float r = sigf(gi[b] + gh[b]);
  float z = sigf(gi[b + HH] + gh[b + HH]);
  float nn = tanhf(gi[b + 2 * HH] + r * gh[b + 2 * HH]);
  float h = (float)hbf[i];
  float hnew = (1.f - z) * nn + z * h;
  hbf[i] = (bf16)hnew;
  dout[(long)(t + 1) * BB * HH + i] = hnew;
}

extern "C" void kernel_launch(void* const* d_in, const int* in_sizes, int n_in,
                              void* d_out, int out_size, void* d_ws, size_t ws_size,
                              hipStream_t stream) {
  const float* obs  = (const float*)d_in[0];
  const float* act  = (const float*)d_in[1];
  const float* eps  = (const float*)d_in[2];
  const float* aggrW = (const float*)d_in[3];
  const float* aggrB = (const float*)d_in[4];
  const float* gWih = (const float*)d_in[5];
  const float* gWhh = (const float*)d_in[6];
  const float* gbih = (const float*)d_in[7];
  const float* gbhh = (const float*)d_in[8];
  const float* qW1  = (const float*)d_in[9];
  const float* qb1  = (const float*)d_in[10];
  const float* qWm  = (const float*)d_in[11];
  const float* qbm  = (const float*)d_in[12];
  const float* qWs  = (const float*)d_in[13];
  const float* qbs  = (const float*)d_in[14];
  const float* pW1  = (const float*)d_in[15];
  const float* pb1  = (const float*)d_in[16];
  const float* pWm  = (const float*)d_in[17];
  const float* pbm  = (const float*)d_in[18];
  const float* pWs  = (const float*)d_in[19];
  const float* pbs  = (const float*)d_in[20];
  float* dout = (float*)d_out;

  char* w = (char*)d_ws;
  size_t off = 0;
  auto alloc = [&](size_t bytes) -> char* {
    char* r = w + off;
    off = (off + bytes + 255) & ~(size_t)255;
    return r;
  };
  bf16* WT_qobs = (bf16*)alloc((size_t)XX * HH * 2);          // q_W1[:X]^T
  bf16* WT_h   = (bf16*)alloc((size_t)5120 * 1024 * 2);       // [qW1[X:] | pW1 | Whh]^T
  bf16* WT_k2  = (bf16*)alloc((size_t)1024 * 1024 * 2);       // [qWm|qWs|pWm|pWs]^T
  bf16* WT_ag  = (bf16*)alloc((size_t)1024 * 320 * 2);        // aggr_W^T (full K=320)
  bf16* WT_ih  = (bf16*)alloc((size_t)3072 * 1024 * 2);       // Wih^T
  bf16* obs_pre = (bf16*)alloc((size_t)TT * BB * HH * 2);
  bf16* act_bf = (bf16*)alloc((size_t)TT * BB * AA * 2);
  bf16* h_bf   = (bf16*)alloc((size_t)BB * HH * 2);
  bf16* hid_q  = (bf16*)alloc((size_t)BB * HH * 2);
  bf16* hid_p  = (bf16*)alloc((size_t)BB * HH * 2);
  bf16* z_bf   = (bf16*)alloc((size_t)BB * ZZ * 2);
  bf16* a_buf  = (bf16*)alloc((size_t)BB * HH * 2);
  float* gh_f  = (float*)alloc((size_t)BB * 3 * HH * 4);
  float* gi_f  = (float*)alloc((size_t)BB * 3 * HH * 4);
  (void)ws_size; (void)in_sizes; (void)n_in; (void)out_size;

  dim3 tb(32, 8);
  transpose_cvt<<<dim3(32, 32), tb, 0, stream>>>(qW1, WT_qobs, 1024, 1024, 1024, 0);
  transpose_cvt<<<dim3(32, 32), tb, 0, stream>>>(qW1, WT_h, 1024, 1024, 1024, 1024);
  transpose_cvt<<<dim3(32, 32), tb, 0, stream>>>(pW1, WT_h + 1024 * 1024, 1024, 1024, 1024, 0);
  transpose_cvt<<<dim3(96, 32), tb, 0, stream>>>(gWhh, WT_h + 2048 * 1024, 1024, 3072, 3072, 0);
  transpose_cvt<<<dim3(8, 32), tb, 0, stream>>>(qWm, WT_k2, 1024, 256, 256, 0);
  transpose_cvt<<<dim3(8, 32), tb, 0, stream>>>(qWs, WT_k2 + 256 * 1024, 1024, 256, 256, 0);
  transpose_cvt<<<dim3(8, 32), tb, 0, stream>>>(pWm, WT_k2 + 512 * 1024, 1024, 256, 256, 0);
  transpose_cvt<<<dim3(8, 32), tb, 0, stream>>>(pWs, WT_k2 + 768 * 1024, 1024, 256, 256, 0);
  transpose_cvt<<<dim3(32, 10), tb, 0, stream>>>(aggrW, WT_ag, 320, 1024, 1024, 0);
  transpose_cvt<<<dim3(96, 32), tb, 0, stream>>>(gWih, WT_ih, 1024, 3072, 3072, 0);
  cvt_bf16<<<TT * BB * AA / 4 / 256, 256, 0, stream>>>(act, act_bf, (long)TT * BB * AA);
  init_k<<<BB * HH / 256, 256, 0, stream>>>(h_bf, dout);

  GArgs g{};
  g.b_q1 = qb1; g.b_p1 = pb1; g.b_ghh = gbhh; g.b_gih = gbih;
  g.b_qm = qbm; g.b_qs = qbs; g.b_pm = pbm; g.b_ps = pbs; g.b_ag = aggrB;
  g.obs_pre = obs_pre; g.hid_q = hid_q; g.hid_p = hid_p; g.a_buf = a_buf;
  g.gh = gh_f; g.gi = gi_f; g.dout = dout;

  {  // obs_pre = obs @ qW1[:X]  (fully parallel, M = T*B)
    GArgs a = g;
    a.Af = obs; a.lda = XX; a.Bt = WT_qobs;
    a.M = TT * BB; a.N = HH; a.K = XX; a.out_bf = obs_pre;
    gemm_k<128, 128, 0, true><<<(TT * BB / 128) * (HH / 128), 256, 0, stream>>>(a);
  }

  for (int t = 0; t < TT; ++t) {
    {  // K1: h @ [qW1_h | pW1 | Whh], N=5120
      GArgs a = g; a.t = t;
      a.A = h_bf; a.lda = HH; a.Bt = WT_h;
      a.M = BB; a.N = 5120; a.K = HH;
      gemm_k<64, 128, 1, false><<<(BB / 64) * (5120 / 128), 256, 0, stream>>>(a);
    }
    {  // K2: [hid_q|hid_p] @ heads, N=1024
      GArgs a = g; a.t = t;
      a.A = hid_q; a.A2 = hid_p; a.lda = HH; a.Bt = WT_k2;
      a.M = BB; a.N = 1024; a.K = HH;
      gemm_k<64, 128, 2, false><<<(BB / 64) * (1024 / 128), 256, 0, stream>>>(a);
    }
    zq_k<<<BB * ZZ / 256, 256, 0, stream>>>(eps, dout, z_bf, t);
    {  // K3: [z_q | act_t] @ aggr_W, K=320
      GArgs a = g; a.t = t;
      a.A = z_bf; a.lda = ZZ;
      a.A2 = act_bf + (size_t)t * BB * AA; a.lda2 = AA; a.ksplit = ZZ;
      a.Bt = WT_ag; a.M = BB; a.N = 1024; a.K = ZZ + AA;
      gemm_k<64, 128, 3, false><<<(BB / 64) * (1024 / 128), 256, 0, stream>>>(a);
    }
    {  // K4: a @ Wih, N=3072
      GArgs a = g; a.t = t;
      a.A = a_buf; a.lda = HH; a.Bt = WT_ih;
      a.M = BB; a.N = 3 * HH; a.K = HH;
      gemm_k<64, 128, 4, false><<<(BB / 64) * (3 * HH / 128), 256, 0, stream>>>(a);
    }
    gates_k<<<BB * HH / 256, 256, 0, stream>>>(gi_f, gh_f, h_bf, dout, t);
  }
}